// Round 11
// baseline (202.022 us; speedup 1.0000x reference)
//
#include <hip/hip_runtime.h>

#define NROWS 32768
#define DDIM  128
#define KCODES 1024
#define DECAY 0.99f
#define OMD   0.01f
#define EPS   1e-5f

typedef __attribute__((ext_vector_type(8))) short short8;
typedef __attribute__((ext_vector_type(4))) float f32x4;

// ws layout (float offsets): [counts 1024][offs i32 1024][inv 1024][bucket i32 32768]
#define WS_COUNTS 0
#define WS_OFFS   1024
#define WS_INV    2048
#define WS_BUCKET 3072

__device__ __forceinline__ unsigned int f2bf(float f) {
  union { float f; unsigned int u; } cv; cv.f = f;
  unsigned int u = cv.u;
  return (u + 0x7fffu + ((u >> 16) & 1u)) >> 16;  // RNE
}

// ---- K1: MFMA scoring, fully self-contained (no pack kernels, no norms kernel).
// Block = 2 M-tiles (32 rows); wave w = code quarter (256 codes, 16 chunks).
// A: 2x8 short8 = 64 VGPRs (allocator-safe size). B: raw fp32 from L2, split to
// (h,l) bf16 in-kernel; exact fp32 norm accumulated from the same loaded values.
// K=384 compensated: xh.eh + xl.eh + xh.el. No barriers until final merge. ----
__global__ __launch_bounds__(256) void vq_mfma(
    const float* __restrict__ x, const float* __restrict__ embed,
    float* __restrict__ out_ind) {
  __shared__ unsigned long long keys[4][32];
  const int tid = threadIdx.x;
  const int w = tid >> 6, lane = tid & 63;
  const int c = lane & 15, q = lane >> 4;
  const int mt0 = blockIdx.x * 2;

  // A fragments from x: 2 M-tiles x (xh 0-3, xl 4-7)
  short8 a[2][8];
  #pragma unroll
  for (int t = 0; t < 2; ++t) {
    const float* xp = x + (size_t)((mt0 + t) * 16 + c) * DDIM + q * 8;
    #pragma unroll
    for (int kb = 0; kb < 4; ++kb) {
      float4 v0 = *(const float4*)(xp + kb * 32);
      float4 v1 = *(const float4*)(xp + kb * 32 + 4);
      float v[8] = {v0.x, v0.y, v0.z, v0.w, v1.x, v1.y, v1.z, v1.w};
      short8 hh, ll;
      #pragma unroll
      for (int j = 0; j < 8; ++j) {
        unsigned int hv = f2bf(v[j]);
        hh[j] = (short)hv;
        float fh = __uint_as_float(hv << 16);
        ll[j] = (short)f2bf(v[j] - fh);
      }
      a[t][kb] = hh;
      a[t][kb + 4] = ll;
    }
  }

  float bestv[8]; int besti[8];
  #pragma unroll
  for (int i = 0; i < 8; ++i) { bestv[i] = -3.4e38f; besti[i] = 0; }

  const int cbase = w * 256;
  for (int ch = 0; ch < 16; ++ch) {
    const int crow = cbase + ch * 16 + c;           // this lane's code
    const float* ep = embed + (size_t)crow * DDIM + q * 8;
    float nhq = 0.f;
    short8 sh[4], sl[4];
    #pragma unroll
    for (int kb = 0; kb < 4; ++kb) {
      float4 v0 = *(const float4*)(ep + kb * 32);
      float4 v1 = *(const float4*)(ep + kb * 32 + 4);
      float v[8] = {v0.x, v0.y, v0.z, v0.w, v1.x, v1.y, v1.z, v1.w};
      short8 hh, ll;
      #pragma unroll
      for (int j = 0; j < 8; ++j) {
        nhq += v[j] * v[j];                         // exact fp32 norm, free load reuse
        unsigned int hv = f2bf(v[j]);
        hh[j] = (short)hv;
        float fh = __uint_as_float(hv << 16);
        ll[j] = (short)f2bf(v[j] - fh);
      }
      sh[kb] = hh;
      sl[kb] = ll;
    }
    nhq += __shfl_xor(nhq, 16, 64);                 // fold the 4 q-quarters
    nhq += __shfl_xor(nhq, 32, 64);
    const float nh = 0.5f * nhq;

    f32x4 acc0 = {0.f, 0.f, 0.f, 0.f}, acc1 = {0.f, 0.f, 0.f, 0.f};
    #pragma unroll
    for (int kb = 0; kb < 4; ++kb) {                // xh . eh
      acc0 = __builtin_amdgcn_mfma_f32_16x16x32_bf16(a[0][kb], sh[kb], acc0, 0, 0, 0);
      acc1 = __builtin_amdgcn_mfma_f32_16x16x32_bf16(a[1][kb], sh[kb], acc1, 0, 0, 0);
    }
    #pragma unroll
    for (int kb = 0; kb < 4; ++kb) {                // xl . eh
      acc0 = __builtin_amdgcn_mfma_f32_16x16x32_bf16(a[0][kb + 4], sh[kb], acc0, 0, 0, 0);
      acc1 = __builtin_amdgcn_mfma_f32_16x16x32_bf16(a[1][kb + 4], sh[kb], acc1, 0, 0, 0);
    }
    #pragma unroll
    for (int kb = 0; kb < 4; ++kb) {                // xh . el
      acc0 = __builtin_amdgcn_mfma_f32_16x16x32_bf16(a[0][kb], sl[kb], acc0, 0, 0, 0);
      acc1 = __builtin_amdgcn_mfma_f32_16x16x32_bf16(a[1][kb], sl[kb], acc1, 0, 0, 0);
    }
    #pragma unroll
    for (int r = 0; r < 4; ++r) {                   // C/D: col=lane&15, row=q*4+r
      float s0 = acc0[r] - nh;
      if (s0 > bestv[r])     { bestv[r] = s0;     besti[r] = crow; }
      float s1 = acc1[r] - nh;
      if (s1 > bestv[4 + r]) { bestv[4 + r] = s1; besti[4 + r] = crow; }
    }
  }

  // fold across the 16 code-columns (lanes sharing q)
  #pragma unroll
  for (int off = 1; off < 16; off <<= 1) {
    #pragma unroll
    for (int i = 0; i < 8; ++i) {
      float ov = __shfl_xor(bestv[i], off, 64);
      int   oi = __shfl_xor(besti[i], off, 64);
      if (ov > bestv[i] || (ov == bestv[i] && oi < besti[i])) {
        bestv[i] = ov; besti[i] = oi;               // first-max (lowest idx) ties
      }
    }
  }
  if (c == 0) {
    #pragma unroll
    for (int t = 0; t < 2; ++t)
      #pragma unroll
      for (int r = 0; r < 4; ++r) {
        unsigned u = __float_as_uint(bestv[t * 4 + r]);
        unsigned su = (u & 0x80000000u) ? ~u : (u | 0x80000000u);
        keys[w][t * 16 + q * 4 + r] =
            ((unsigned long long)su << 32) |
            (unsigned long long)(0xFFFFFFFFu - (unsigned)besti[t * 4 + r]);
      }
  }
  __syncthreads();
  if (tid < 32) {                                   // merge 4 code-quarters
    unsigned long long k0 = keys[0][tid], k1 = keys[1][tid];
    unsigned long long k2 = keys[2][tid], k3 = keys[3][tid];
    unsigned long long k = k0 > k1 ? k0 : k1;
    if (k2 > k) k = k2;
    if (k3 > k) k = k3;
    int code = (int)(0xFFFFFFFFu - (unsigned)(k & 0xFFFFFFFFull));
    out_ind[blockIdx.x * 32 + tid] = (float)code;
  }
}

// ---- K2: one-block fusion of histogram + scan + EMA-size/inv + bucket scatter ----
__global__ __launch_bounds__(1024) void scanall(
    const float* __restrict__ out_ind, const float* __restrict__ cs,
    float* __restrict__ counts_g, int* __restrict__ offs, float* __restrict__ inv,
    int* __restrict__ bucket, float* __restrict__ out_ncs) {
  __shared__ int hist[1024];
  __shared__ int cur[1024];
  __shared__ float wtot[16], ctot[16];
  const int tid = threadIdx.x;
  const int lane = tid & 63, w = tid >> 6;
  int codes[32];
  hist[tid] = 0;
  __syncthreads();
  #pragma unroll
  for (int i = 0; i < 32; ++i) {
    codes[i] = (int)out_ind[i * 1024 + tid];
    atomicAdd(&hist[codes[i]], 1);
  }
  __syncthreads();
  const int cnt = hist[tid];
  const float cnum = (float)cnt;
  const float cv = cs[tid];
  float s = cnum;
  #pragma unroll
  for (int off = 1; off < 64; off <<= 1) {
    float v = __shfl_up(s, off, 64);
    if (lane >= off) s += v;
  }
  float r2 = cv;
  #pragma unroll
  for (int off = 32; off > 0; off >>= 1) r2 += __shfl_down(r2, off, 64);
  if (lane == 63) wtot[w] = s;
  if (lane == 0)  ctot[w] = r2;
  __syncthreads();
  if (tid < 16) {
    float v = wtot[tid];
    #pragma unroll
    for (int off = 1; off < 16; off <<= 1) {
      float p = __shfl_up(v, off, 64);
      if (tid >= off) v += p;
    }
    wtot[tid] = v;
    float t2 = ctot[tid];
    #pragma unroll
    for (int off = 8; off > 0; off >>= 1) t2 += __shfl_down(t2, off, 64);
    if (tid == 0) ctot[0] = t2;
  }
  __syncthreads();
  const float prefix = (w > 0) ? wtot[w - 1] : 0.f;
  const int excl = (int)(s + prefix) - cnt;
  offs[tid] = excl;
  cur[tid] = excl;
  counts_g[tid] = cnum;
  const float ncs = cv * DECAY + OMD * cnum;
  out_ncs[tid] = ncs;
  const float total = ctot[0] * DECAY + OMD * (float)NROWS;  // sum(ncs) decomposed
  inv[tid] = (total + (float)KCODES * EPS) / ((ncs + EPS) * total);
  __syncthreads();
  #pragma unroll
  for (int i = 0; i < 32; ++i) {
    int pos = atomicAdd(&cur[codes[i]], 1);
    bucket[pos] = i * 1024 + tid;
  }
}

// ---- K3: per-code segmented reduction + quantize write + fused EMA epilogue ----
__global__ __launch_bounds__(256) void esum_q_fin(
    const int* __restrict__ bucket, const int* __restrict__ offs,
    const float* __restrict__ counts, const float* __restrict__ x,
    const float* __restrict__ embed, const float* __restrict__ ea,
    const float* __restrict__ inv,
    float* __restrict__ out_q, float* __restrict__ out_nea, float* __restrict__ out_ne) {
  __shared__ float4 part[512];
  const int code = blockIdx.x;
  const int t = threadIdx.x;
  const int c8 = t & 15;
  const int h = t >> 4;
  const int start = offs[code];
  const int cnt = (int)counts[code];
  const float4 e0 = *(const float4*)(embed + (size_t)code * DDIM + c8 * 8);
  const float4 e1 = *(const float4*)(embed + (size_t)code * DDIM + c8 * 8 + 4);
  float4 a0 = {0.f, 0.f, 0.f, 0.f}, a1 = {0.f, 0.f, 0.f, 0.f};
  int i = h;
  for (; i + 16 < cnt; i += 32) {
    int rowA = bucket[start + i];
    int rowB = bucket[start + i + 16];
    const float* pa = x + (size_t)rowA * DDIM + c8 * 8;
    const float* pb = x + (size_t)rowB * DDIM + c8 * 8;
    float4 xa0 = *(const float4*)(pa), xa1 = *(const float4*)(pa + 4);
    float4 xb0 = *(const float4*)(pb), xb1 = *(const float4*)(pb + 4);
    float* qa = out_q + (size_t)rowA * DDIM + c8 * 8;
    float* qb = out_q + (size_t)rowB * DDIM + c8 * 8;
    *(float4*)(qa) = e0; *(float4*)(qa + 4) = e1;
    *(float4*)(qb) = e0; *(float4*)(qb + 4) = e1;
    a0.x += xa0.x + xb0.x; a0.y += xa0.y + xb0.y; a0.z += xa0.z + xb0.z; a0.w += xa0.w + xb0.w;
    a1.x += xa1.x + xb1.x; a1.y += xa1.y + xb1.y; a1.z += xa1.z + xb1.z; a1.w += xa1.w + xb1.w;
  }
  for (; i < cnt; i += 16) {
    int row = bucket[start + i];
    const float* pa = x + (size_t)row * DDIM + c8 * 8;
    float4 xa0 = *(const float4*)(pa), xa1 = *(const float4*)(pa + 4);
    float* qa = out_q + (size_t)row * DDIM + c8 * 8;
    *(float4*)(qa) = e0; *(float4*)(qa + 4) = e1;
    a0.x += xa0.x; a0.y += xa0.y; a0.z += xa0.z; a0.w += xa0.w;
    a1.x += xa1.x; a1.y += xa1.y; a1.z += xa1.z; a1.w += xa1.w;
  }
  part[h * 32 + c8 * 2]     = a0;
  part[h * 32 + c8 * 2 + 1] = a1;
  __syncthreads();
  if (t < 32) {
    float4 s = part[t];
    #pragma unroll
    for (int hh = 1; hh < 16; ++hh) {
      float4 p = part[hh * 32 + t];
      s.x += p.x; s.y += p.y; s.z += p.z; s.w += p.w;
    }
    float iv = inv[code];
    int base = code * DDIM + t * 4;
    float4 a = *(const float4*)(ea + base);
    float4 nea;
    nea.x = a.x * DECAY + OMD * s.x; nea.y = a.y * DECAY + OMD * s.y;
    nea.z = a.z * DECAY + OMD * s.z; nea.w = a.w * DECAY + OMD * s.w;
    *(float4*)(out_nea + base) = nea;
    float4 ne;
    ne.x = nea.x * iv; ne.y = nea.y * iv; ne.z = nea.z * iv; ne.w = nea.w * iv;
    *(float4*)(out_ne + base) = ne;
  }
}

extern "C" void kernel_launch(void* const* d_in, const int* in_sizes, int n_in,
                              void* d_out, int out_size, void* d_ws, size_t ws_size,
                              hipStream_t stream) {
  const float* x     = (const float*)d_in[0];
  const float* embed = (const float*)d_in[1];
  const float* cs    = (const float*)d_in[2];
  const float* ea    = (const float*)d_in[3];

  float* out     = (float*)d_out;
  float* out_q   = out;                       // 4194304
  float* out_ind = out_q + 4194304;           // 32768
  float* out_ncs = out_ind + 32768;           // 1024
  float* out_nea = out_ncs + 1024;            // 131072
  float* out_ne  = out_nea + 131072;          // 131072

  float* ws     = (float*)d_ws;
  float* counts = ws + WS_COUNTS;
  int*   offs   = (int*)(ws + WS_OFFS);
  float* inv    = ws + WS_INV;
  int*   bucket = (int*)(ws + WS_BUCKET);

  vq_mfma<<<NROWS / 32, 256, 0, stream>>>(x, embed, out_ind);
  scanall<<<1, 1024, 0, stream>>>(out_ind, cs, counts, offs, inv, bucket, out_ncs);
  esum_q_fin<<<KCODES, 256, 0, stream>>>(bucket, offs, counts, x, embed, ea, inv,
                                         out_q, out_nea, out_ne);
}

// Round 12
// 171.313 us; speedup vs baseline: 1.1793x; 1.1793x over previous
//
#include <hip/hip_runtime.h>

#define NROWS 32768
#define DDIM  128
#define KCODES 1024
#define DECAY 0.99f
#define OMD   0.01f
#define EPS   1e-5f

typedef __attribute__((ext_vector_type(8))) short short8;
typedef __attribute__((ext_vector_type(4))) float f32x4;

// ws layout (float offsets): [counts 1024][offs i32 1024][cursor i32 1024][inv 1024][en2h 1024][bucket i32 32768]
#define WS_COUNTS 0
#define WS_OFFS   1024
#define WS_CURSOR 2048
#define WS_INV    3072
#define WS_EN2H   4096
#define WS_BUCKET 5120

__device__ __forceinline__ unsigned int f2bf(float f) {
  union { float f; unsigned int u; } cv; cv.f = f;
  unsigned int u = cv.u;
  return (u + 0x7fffu + ((u >> 16) & 1u)) >> 16;  // RNE
}

// ---- K1: split embed into (eh, el) bf16, MFMA B-fragment layout + exact norms.
// epack frag (nt, j): j 0-3 = eh, j 4-7 = el. 512 KB, aliased into out_nea. ----
__global__ __launch_bounds__(256) void pack_e(const float* __restrict__ embed,
                                              ushort* __restrict__ epack,
                                              float* __restrict__ en2h) {
  const int tid = threadIdx.x;
  const int w = tid >> 6, lane = tid & 63;
  const int nt = blockIdx.x * 4 + w;          // 64 tiles of 16 codes
  const int m = lane & 15, q = lane >> 4;
  const int row = nt * 16 + m;
  const float* ep = embed + (size_t)row * DDIM + q * 8;
  float ss = 0.f;
  #pragma unroll
  for (int kb = 0; kb < 4; ++kb) {
    float4 v0 = *(const float4*)(ep + kb * 32);
    float4 v1 = *(const float4*)(ep + kb * 32 + 4);
    float v[8] = {v0.x, v0.y, v0.z, v0.w, v1.x, v1.y, v1.z, v1.w};
    unsigned int h[8], l[8];
    #pragma unroll
    for (int j = 0; j < 8; ++j) {
      ss += v[j] * v[j];
      h[j] = f2bf(v[j]);
      float fh = __uint_as_float(h[j] << 16);
      l[j] = f2bf(v[j] - fh);
    }
    uint4 ph, pl;
    ph.x = h[0] | (h[1] << 16); ph.y = h[2] | (h[3] << 16);
    ph.z = h[4] | (h[5] << 16); ph.w = h[6] | (h[7] << 16);
    pl.x = l[0] | (l[1] << 16); pl.y = l[2] | (l[3] << 16);
    pl.z = l[4] | (l[5] << 16); pl.w = l[6] | (l[7] << 16);
    *(uint4*)(epack + (((size_t)nt * 8 + kb) * 64 + lane) * 8)     = ph;  // eh
    *(uint4*)(epack + (((size_t)nt * 8 + kb + 4) * 64 + lane) * 8) = pl;  // el
  }
  ss += __shfl_xor(ss, 16, 64);
  ss += __shfl_xor(ss, 32, 64);
  if (q == 0) en2h[row] = 0.5f * ss;
}

// ---- K2: MFMA scoring + fused quantize write.
// Block = 2 M-tiles (32 rows), resident A (64 VGPRs, built in-kernel from x);
// wave w = code quarter, B = pre-packed ep8 loads (L2-hot), no conversion.
// K=384 compensated: xh.eh + xl.eh + xh.el. ----
__global__ __launch_bounds__(256) void vq_mfma(
    const float* __restrict__ x, const short8* __restrict__ ep8,
    const float* __restrict__ en2h, const float* __restrict__ embed,
    float* __restrict__ out_ind, float* __restrict__ out_q) {
  __shared__ unsigned long long keys[4][32];
  __shared__ int scodes[32];
  const int tid = threadIdx.x;
  const int w = tid >> 6, lane = tid & 63;
  const int c = lane & 15, q = lane >> 4;
  const int mt0 = blockIdx.x * 2;

  // A fragments from x: 2 M-tiles x (xh 0-3, xl 4-7) = 64 VGPRs
  short8 a[2][8];
  #pragma unroll
  for (int t = 0; t < 2; ++t) {
    const float* xp = x + (size_t)((mt0 + t) * 16 + c) * DDIM + q * 8;
    #pragma unroll
    for (int kb = 0; kb < 4; ++kb) {
      float4 v0 = *(const float4*)(xp + kb * 32);
      float4 v1 = *(const float4*)(xp + kb * 32 + 4);
      float v[8] = {v0.x, v0.y, v0.z, v0.w, v1.x, v1.y, v1.z, v1.w};
      short8 hh, ll;
      #pragma unroll
      for (int j = 0; j < 8; ++j) {
        unsigned int hv = f2bf(v[j]);
        hh[j] = (short)hv;
        float fh = __uint_as_float(hv << 16);
        ll[j] = (short)f2bf(v[j] - fh);
      }
      a[t][kb] = hh;
      a[t][kb + 4] = ll;
    }
  }

  float bestv[8]; int besti[8];
  #pragma unroll
  for (int i = 0; i < 8; ++i) { bestv[i] = -3.4e38f; besti[i] = 0; }

  const int nt0 = w * 16;
  for (int ch = 0; ch < 16; ++ch) {
    const int nt = nt0 + ch;
    short8 st[8];                             // eh 0-3, el 4-7
    #pragma unroll
    for (int j = 0; j < 8; ++j)
      st[j] = ep8[((size_t)nt * 8 + j) * 64 + lane];
    const float nh = en2h[nt * 16 + c];
    f32x4 acc0 = {0.f, 0.f, 0.f, 0.f}, acc1 = {0.f, 0.f, 0.f, 0.f};
    #pragma unroll
    for (int kb = 0; kb < 4; ++kb) {          // xh . eh
      acc0 = __builtin_amdgcn_mfma_f32_16x16x32_bf16(a[0][kb], st[kb], acc0, 0, 0, 0);
      acc1 = __builtin_amdgcn_mfma_f32_16x16x32_bf16(a[1][kb], st[kb], acc1, 0, 0, 0);
    }
    #pragma unroll
    for (int kb = 0; kb < 4; ++kb) {          // xl . eh
      acc0 = __builtin_amdgcn_mfma_f32_16x16x32_bf16(a[0][kb + 4], st[kb], acc0, 0, 0, 0);
      acc1 = __builtin_amdgcn_mfma_f32_16x16x32_bf16(a[1][kb + 4], st[kb], acc1, 0, 0, 0);
    }
    #pragma unroll
    for (int kb = 0; kb < 4; ++kb) {          // xh . el
      acc0 = __builtin_amdgcn_mfma_f32_16x16x32_bf16(a[0][kb], st[kb + 4], acc0, 0, 0, 0);
      acc1 = __builtin_amdgcn_mfma_f32_16x16x32_bf16(a[1][kb], st[kb + 4], acc1, 0, 0, 0);
    }
    const int code = nt * 16 + c;
    #pragma unroll
    for (int r = 0; r < 4; ++r) {             // C/D: col=lane&15, row=q*4+r
      float s0 = acc0[r] - nh;
      if (s0 > bestv[r])     { bestv[r] = s0;     besti[r] = code; }
      float s1 = acc1[r] - nh;
      if (s1 > bestv[4 + r]) { bestv[4 + r] = s1; besti[4 + r] = code; }
    }
  }

  // fold across the 16 code-columns (lanes sharing q)
  #pragma unroll
  for (int off = 1; off < 16; off <<= 1) {
    #pragma unroll
    for (int i = 0; i < 8; ++i) {
      float ov = __shfl_xor(bestv[i], off, 64);
      int   oi = __shfl_xor(besti[i], off, 64);
      if (ov > bestv[i] || (ov == bestv[i] && oi < besti[i])) {
        bestv[i] = ov; besti[i] = oi;         // first-max (lowest idx) ties
      }
    }
  }
  if (c == 0) {
    #pragma unroll
    for (int t = 0; t < 2; ++t)
      #pragma unroll
      for (int r = 0; r < 4; ++r) {
        unsigned u = __float_as_uint(bestv[t * 4 + r]);
        unsigned su = (u & 0x80000000u) ? ~u : (u | 0x80000000u);
        keys[w][t * 16 + q * 4 + r] =
            ((unsigned long long)su << 32) |
            (unsigned long long)(0xFFFFFFFFu - (unsigned)besti[t * 4 + r]);
      }
  }
  __syncthreads();
  if (tid < 32) {                             // merge 4 code-quarters
    unsigned long long k0 = keys[0][tid], k1 = keys[1][tid];
    unsigned long long k2 = keys[2][tid], k3 = keys[3][tid];
    unsigned long long k = k0 > k1 ? k0 : k1;
    if (k2 > k) k = k2;
    if (k3 > k) k = k3;
    int code = (int)(0xFFFFFFFFu - (unsigned)(k & 0xFFFFFFFFull));
    out_ind[blockIdx.x * 32 + tid] = (float)code;
    scodes[tid] = code;
  }
  __syncthreads();
  // fused quantize write: 32 rows x 32 float4 = 1024 float4, 4 per thread
  #pragma unroll
  for (int it = 0; it < 4; ++it) {
    int idx = tid + it * 256;
    int row = idx >> 5, c4 = idx & 31;
    int code = scodes[row];
    *(float4*)(out_q + (size_t)(blockIdx.x * 32 + row) * DDIM + c4 * 4) =
        *(const float4*)(embed + (size_t)code * DDIM + c4 * 4);
  }
}

// ---- K3: histogram + scan + EMA-size/inv (one block; no scatter here) ----
__global__ __launch_bounds__(1024) void scan_fin(
    const float* __restrict__ out_ind, const float* __restrict__ cs,
    float* __restrict__ counts_g, int* __restrict__ offs, int* __restrict__ cursor,
    float* __restrict__ inv, float* __restrict__ out_ncs) {
  __shared__ int hist[1024];
  __shared__ float wtot[16], ctot[16];
  const int tid = threadIdx.x;
  const int lane = tid & 63, w = tid >> 6;
  hist[tid] = 0;
  __syncthreads();
  #pragma unroll
  for (int i = 0; i < 32; ++i)
    atomicAdd(&hist[(int)out_ind[i * 1024 + tid]], 1);
  __syncthreads();
  const int cnt = hist[tid];
  const float cnum = (float)cnt;
  const float cv = cs[tid];
  float s = cnum;
  #pragma unroll
  for (int off = 1; off < 64; off <<= 1) {
    float v = __shfl_up(s, off, 64);
    if (lane >= off) s += v;
  }
  float r2 = cv;
  #pragma unroll
  for (int off = 32; off > 0; off >>= 1) r2 += __shfl_down(r2, off, 64);
  if (lane == 63) wtot[w] = s;
  if (lane == 0)  ctot[w] = r2;
  __syncthreads();
  if (tid < 16) {
    float v = wtot[tid];
    #pragma unroll
    for (int off = 1; off < 16; off <<= 1) {
      float p = __shfl_up(v, off, 64);
      if (tid >= off) v += p;
    }
    wtot[tid] = v;
    float t2 = ctot[tid];
    #pragma unroll
    for (int off = 8; off > 0; off >>= 1) t2 += __shfl_down(t2, off, 64);
    if (tid == 0) ctot[0] = t2;
  }
  __syncthreads();
  const float prefix = (w > 0) ? wtot[w - 1] : 0.f;
  const int excl = (int)(s + prefix) - cnt;
  offs[tid] = excl;
  cursor[tid] = excl;
  counts_g[tid] = cnum;
  const float ncs = cv * DECAY + OMD * cnum;
  out_ncs[tid] = ncs;
  const float total = ctot[0] * DECAY + OMD * (float)NROWS;  // sum(ncs) decomposed
  inv[tid] = (total + (float)KCODES * EPS) / ((ncs + EPS) * total);
}

// ---- K4: scatter row ids into per-code buckets (parallel, global cursors) ----
__global__ void scatter_rows(const float* __restrict__ out_ind,
                             int* __restrict__ cursor, int* __restrict__ bucket) {
  int row = blockIdx.x * 256 + threadIdx.x;
  int code = (int)out_ind[row];
  int pos = atomicAdd(cursor + code, 1);
  bucket[pos] = row;
}

// ---- K5: per-code segmented reduction + fused EMA epilogue (no out_q) ----
__global__ __launch_bounds__(256) void esum_fin(
    const int* __restrict__ bucket, const int* __restrict__ offs,
    const float* __restrict__ counts, const float* __restrict__ x,
    const float* __restrict__ ea, const float* __restrict__ inv,
    float* __restrict__ out_nea, float* __restrict__ out_ne) {
  __shared__ float4 part[512];
  const int code = blockIdx.x;
  const int t = threadIdx.x;
  const int c8 = t & 15;
  const int h = t >> 4;
  const int start = offs[code];
  const int cnt = (int)counts[code];
  float4 a0 = {0.f, 0.f, 0.f, 0.f}, a1 = {0.f, 0.f, 0.f, 0.f};
  int i = h;
  for (; i + 16 < cnt; i += 32) {
    int rowA = bucket[start + i];
    int rowB = bucket[start + i + 16];
    const float* pa = x + (size_t)rowA * DDIM + c8 * 8;
    const float* pb = x + (size_t)rowB * DDIM + c8 * 8;
    float4 xa0 = *(const float4*)(pa), xa1 = *(const float4*)(pa + 4);
    float4 xb0 = *(const float4*)(pb), xb1 = *(const float4*)(pb + 4);
    a0.x += xa0.x + xb0.x; a0.y += xa0.y + xb0.y; a0.z += xa0.z + xb0.z; a0.w += xa0.w + xb0.w;
    a1.x += xa1.x + xb1.x; a1.y += xa1.y + xb1.y; a1.z += xa1.z + xb1.z; a1.w += xa1.w + xb1.w;
  }
  for (; i < cnt; i += 16) {
    int row = bucket[start + i];
    const float* pa = x + (size_t)row * DDIM + c8 * 8;
    float4 xa0 = *(const float4*)(pa), xa1 = *(const float4*)(pa + 4);
    a0.x += xa0.x; a0.y += xa0.y; a0.z += xa0.z; a0.w += xa0.w;
    a1.x += xa1.x; a1.y += xa1.y; a1.z += xa1.z; a1.w += xa1.w;
  }
  part[h * 32 + c8 * 2]     = a0;
  part[h * 32 + c8 * 2 + 1] = a1;
  __syncthreads();
  if (t < 32) {
    float4 s = part[t];
    #pragma unroll
    for (int hh = 1; hh < 16; ++hh) {
      float4 p = part[hh * 32 + t];
      s.x += p.x; s.y += p.y; s.z += p.z; s.w += p.w;
    }
    float iv = inv[code];
    int base = code * DDIM + t * 4;
    float4 a = *(const float4*)(ea + base);
    float4 nea;
    nea.x = a.x * DECAY + OMD * s.x; nea.y = a.y * DECAY + OMD * s.y;
    nea.z = a.z * DECAY + OMD * s.z; nea.w = a.w * DECAY + OMD * s.w;
    *(float4*)(out_nea + base) = nea;
    float4 ne;
    ne.x = nea.x * iv; ne.y = nea.y * iv; ne.z = nea.z * iv; ne.w = nea.w * iv;
    *(float4*)(out_ne + base) = ne;
  }
}

extern "C" void kernel_launch(void* const* d_in, const int* in_sizes, int n_in,
                              void* d_out, int out_size, void* d_ws, size_t ws_size,
                              hipStream_t stream) {
  const float* x     = (const float*)d_in[0];
  const float* embed = (const float*)d_in[1];
  const float* cs    = (const float*)d_in[2];
  const float* ea    = (const float*)d_in[3];

  float* out     = (float*)d_out;
  float* out_q   = out;                       // 4194304
  float* out_ind = out_q + 4194304;           // 32768
  float* out_ncs = out_ind + 32768;           // 1024
  float* out_nea = out_ncs + 1024;            // 131072
  float* out_ne  = out_nea + 131072;          // 131072

  float* ws     = (float*)d_ws;
  float* counts = ws + WS_COUNTS;
  int*   offs   = (int*)(ws + WS_OFFS);
  int*   cursor = (int*)(ws + WS_CURSOR);
  float* inv    = ws + WS_INV;
  float* en2h   = ws + WS_EN2H;
  int*   bucket = (int*)(ws + WS_BUCKET);

  // epack scratch aliased into out_nea (512 KB); read only by vq_mfma,
  // overwritten later by esum_fin.
  ushort* epack = (ushort*)out_nea;

  pack_e<<<16, 256, 0, stream>>>(embed, epack, en2h);
  vq_mfma<<<NROWS / 32, 256, 0, stream>>>(x, (const short8*)epack, en2h, embed,
                                          out_ind, out_q);
  scan_fin<<<1, 1024, 0, stream>>>(out_ind, cs, counts, offs, cursor, inv, out_ncs);
  scatter_rows<<<NROWS / 256, 256, 0, stream>>>(out_ind, cursor, bucket);
  esum_fin<<<KCODES, 256, 0, stream>>>(bucket, offs, counts, x, ea, inv,
                                       out_nea, out_ne);
}